// Round 4
// baseline (424.649 us; speedup 1.0000x reference)
//
#include <hip/hip_runtime.h>
#include <stdint.h>

#define B_ 4
#define H_ 8
#define T_ 2048
#define C_ 1184
#define DK_ 148
#define DP_ 160
#define C3_ 3552

typedef __attribute__((ext_vector_type(8))) short s8v;
typedef __attribute__((ext_vector_type(4))) short s4v;
typedef __attribute__((ext_vector_type(4))) float f4v;

#define CSC 0.11858886f  /* log2(e)/sqrt(148) */

__device__ __forceinline__ unsigned short f2b(float f) {
  union { float f; unsigned u; } v; v.f = f;
  unsigned r = v.u + 0x7FFFu + ((v.u >> 16) & 1u);
  return (unsigned short)(r >> 16);
}

__device__ __forceinline__ void gld16(const void* g, void* l) {
  __builtin_amdgcn_global_load_lds(
      (const __attribute__((address_space(1))) void*)g,
      (__attribute__((address_space(3))) void*)l, 16, 0, 0);
}

__global__ __launch_bounds__(256) void cvt4(const float* __restrict__ src,
                                            short* __restrict__ dst, int n4) {
  int i = blockIdx.x * 256 + threadIdx.x;
  if (i >= n4) return;
  float4 f = ((const float4*)src)[i];
  s4v o = { (short)f2b(f.x), (short)f2b(f.y), (short)f2b(f.z), (short)f2b(f.w) };
  ((s4v*)dst)[i] = o;
}

// zero the d=148..159 pad of every Q/K row (contraction pads must be 0)
__global__ __launch_bounds__(256) void zpad(short* __restrict__ Qb,
                                            short* __restrict__ Kb) {
  const int row = blockIdx.x * 256 + threadIdx.x;  // 32*2048 rows
  const size_t off = (size_t)row * DP_ + DK_;
  const s4v z = { 0, 0, 0, 0 };
  *(s4v*)(Qb + off) = z; *(s4v*)(Qb + off + 4) = z; *(s4v*)(Qb + off + 8) = z;
  *(s4v*)(Kb + off) = z; *(s4v*)(Kb + off + 4) = z; *(s4v*)(Kb + off + 8) = z;
}

// C = A @ B^T (+bias). 128x128 tile, 4 waves, mfma 16x16x32 bf16, BK=32,
// global_load_lds(16B) staging, double-buffered. XCD-chunked 1D grid.
template <int EPI, int NT>
__global__ __launch_bounds__(256, 2) void gemm_bt(
    const short* __restrict__ A, const short* __restrict__ Bm,
    const float* __restrict__ bias,
    short* __restrict__ Qb, short* __restrict__ Kb, short* __restrict__ Vt,
    float* __restrict__ Out) {
  constexpr int K = C_;
  constexpr int NK = K / 32;  // 37
  __shared__ short As[2][128 * 32];
  __shared__ short Bs[2][128 * 32];
  const int tid = threadIdx.x;
  const int lane = tid & 63;
  const int wid = tid >> 6;
  const int lo = lane & 15, hi = lane >> 4;
  const int bid = blockIdx.x;
  const int xcd = bid & 7;
  const int kk = bid >> 3;
  const int m0 = (xcd * 8 + kk / NT) * 128;
  const int n0 = (kk % NT) * 128;
  const int wr = wid >> 1, wc = wid & 1;

  const int r0 = tid >> 2;
  const int sg = (tid & 3) * 8;
  const short* pa0 = A + (size_t)(m0 + r0) * K + sg;
  const short* pa1 = A + (size_t)(m0 + r0 + 64) * K + sg;
  const short* pb0 = Bm + (size_t)(n0 + r0) * K + sg;
  const short* pb1 = Bm + (size_t)(n0 + r0 + 64) * K + sg;

  f4v acc[4][4] = {};

#define STAGE(kk_, buf)                               \
  do {                                                \
    const int _o = (kk_) * 32;                        \
    gld16(pa0 + _o, &As[(buf)][tid * 8]);             \
    gld16(pa1 + _o, &As[(buf)][(tid + 256) * 8]);     \
    gld16(pb0 + _o, &Bs[(buf)][tid * 8]);             \
    gld16(pb1 + _o, &Bs[(buf)][(tid + 256) * 8]);     \
  } while (0)

  STAGE(0, 0);
  int cur = 0;
  for (int ks = 0; ks < NK; ++ks) {
    __syncthreads();  // drains vmcnt -> buf[cur] ready; buf[cur^1] consumed
    if (ks + 1 < NK) STAGE(ks + 1, cur ^ 1);
    const short* Ab = As[cur];
    const short* Bb = Bs[cur];
    s8v af[4], bf[4];
#pragma unroll
    for (int m = 0; m < 4; ++m)
      af[m] = *(const s8v*)&Ab[(wr * 64 + m * 16 + lo) * 32 + hi * 8];
#pragma unroll
    for (int n = 0; n < 4; ++n)
      bf[n] = *(const s8v*)&Bb[(wc * 64 + n * 16 + lo) * 32 + hi * 8];
#pragma unroll
    for (int m = 0; m < 4; ++m)
#pragma unroll
      for (int n = 0; n < 4; ++n)
        acc[m][n] = __builtin_amdgcn_mfma_f32_16x16x32_bf16(af[m], bf[n], acc[m][n], 0, 0, 0);
    cur ^= 1;
  }
#undef STAGE

#pragma unroll
  for (int n = 0; n < 4; ++n) {
    const int gn = n0 + wc * 64 + n * 16 + lo;
    if (EPI == 0) {
      if (gn < C3_) {
        const float bv = bias[gn];
        const int sel = gn / C_;
        const int r = gn - sel * C_;
        const int h = r / DK_;
        const int d = r - h * DK_;
#pragma unroll
        for (int m = 0; m < 4; ++m) {
          const int t0 = m0 + wr * 64 + m * 16 + hi * 4;
          const int b = t0 >> 11, tt = t0 & 2047;
          const int bh = b * H_ + h;
          if (sel == 2) {  // V^T: 4 consecutive t for fixed d -> vector store
            s4v o = { (short)f2b(acc[m][n][0] + bv), (short)f2b(acc[m][n][1] + bv),
                      (short)f2b(acc[m][n][2] + bv), (short)f2b(acc[m][n][3] + bv) };
            *(s4v*)&Vt[((size_t)bh * DP_ + d) * T_ + tt] = o;
          } else {
#pragma unroll
            for (int j = 0; j < 4; ++j) {
              const short v = (sel == 0) ? (short)f2b((acc[m][n][j] + bv) * CSC)
                                         : (short)f2b(acc[m][n][j] + bv);
              if (sel == 0) Qb[((size_t)bh * T_ + tt + j) * DP_ + d] = v;
              else          Kb[((size_t)bh * T_ + tt + j) * DP_ + d] = v;
            }
          }
        }
      }
    } else {
      if (gn < C_) {
        const float bv = bias[gn];
#pragma unroll
        for (int m = 0; m < 4; ++m)
#pragma unroll
          for (int j = 0; j < 4; ++j) {
            const int gm = m0 + wr * 64 + m * 16 + hi * 4 + j;
            Out[(size_t)gm * C_ + gn] = acc[m][n][j] + bv;
          }
      }
    }
  }
}

// Causal flash attention, block-shared LDS-staged K/V, KVBLK=32, 3 blocks/CU.
// Q (pre-scaled), K: [32][2048][160] bf16 (d pad zeroed), Vt: [32][160][2048].
// Block = 4 waves x 32 q rows; kv tiles of 32, double-buffered global_load_lds
// with source-side XOR swizzle; one barrier per tile; defer-rescale THR=8.
__global__ __launch_bounds__(256, 3) void attn(
    const short* __restrict__ Qb, const short* __restrict__ Kb,
    const short* __restrict__ Vt, short* __restrict__ Y) {
  __shared__ short Ks[2][5120];  // [5 c][32 r][4 w] granules(8sh), w XOR (r>>1)&3
  __shared__ short Vs[2][5120];  // [160 d][4 v] granules, v XOR d&3
  __shared__ short Pl[4][2][16][40];
  const int tid = threadIdx.x;
  const int lane = tid & 63;
  const int wid = tid >> 6;
  const int lo = lane & 15, hi = lane >> 4;
  // XCD-aware balanced remap: xcd owns 4 bh; qb paired with 15-qb for backfill
  const int s = blockIdx.x;
  const int xcd = s & 7;
  const int k = s >> 3;
  int qb, bsub;
  if (k < 32) { bsub = k >> 4; qb = k & 15; }
  else { bsub = 2 + ((k - 32) >> 4); qb = 15 - (k & 15); }
  const int bh = xcd * 4 + bsub;
  const int q0 = qb * 128 + wid * 32;
  const short* Qh = Qb + (size_t)bh * T_ * DP_;
  const short* Kh = Kb + (size_t)bh * T_ * DP_;
  const short* Vh = Vt + (size_t)bh * DP_ * T_;

  // Q B-fragments: lane holds q = q0 + u*16 + lo, d = c*32 + hi*8 .. +7
  s8v qf[2][5];
#pragma unroll
  for (int u = 0; u < 2; ++u)
#pragma unroll
    for (int c = 0; c < 5; ++c)
      qf[u][c] = *(const s8v*)(Qh + (size_t)(q0 + u * 16 + lo) * DP_ + c * 32 + hi * 8);

  f4v acc[10][2] = {};
  float mrun[2] = { -INFINITY, -INFINITY };
  float lrun[2] = { 0.f, 0.f };
  const int swzk = hi ^ ((lo >> 1) & 3);
  const int nt = 4 * (qb + 1);  // uniform across the block's 4 waves

#define STAGEKV(kt_, buf_)                                                    \
  do {                                                                        \
    const int kv_ = (kt_) * 32;                                               \
    _Pragma("unroll")                                                         \
    for (int i_ = 0; i_ < 5; ++i_) {                                          \
      const int gg_ = tid + i_ * 256;                                         \
      if (gg_ < 640) {                                                        \
        const int c_ = gg_ >> 7, re_ = gg_ & 127, r_ = re_ >> 2;              \
        const int w_ = (re_ & 3) ^ ((r_ >> 1) & 3);                           \
        gld16(Kh + (size_t)(kv_ + r_) * DP_ + c_ * 32 + w_ * 8,               \
              &Ks[buf_][gg_ * 8]);                                            \
      } else {                                                                \
        const int gv_ = gg_ - 640;                                            \
        const int d_ = gv_ >> 2;                                              \
        const int v_ = (gv_ & 3) ^ (d_ & 3);                                  \
        gld16(Vh + (size_t)d_ * T_ + kv_ + v_ * 8, &Vs[buf_][gv_ * 8]);       \
      }                                                                       \
    }                                                                         \
  } while (0)

  STAGEKV(0, 0);
  int cur = 0;
  for (int kt = 0; kt < nt; ++kt) {
    __syncthreads();  // stage of buf[cur] drained; buf[cur^1] free
    if (kt + 1 < nt) STAGEKV(kt + 1, cur ^ 1);
    const int kv0 = kt * 32;
    if (kv0 <= q0 + 31) {  // wave-uniform: skip fully-masked tail tiles
      const short* Kc = Ks[cur];
      const short* Vc = Vs[cur];
      // S^T[kv][q] = K . Q^T over 2 kv sub-tiles of 16
      f4v sc[2][2] = {};
#pragma unroll
      for (int t = 0; t < 2; ++t)
#pragma unroll
        for (int c = 0; c < 5; ++c) {
          s8v kf = *(const s8v*)&Kc[(c * 128 + (t * 16 + lo) * 4 + swzk) * 8];
          sc[0][t] = __builtin_amdgcn_mfma_f32_16x16x32_bf16(kf, qf[0][c], sc[0][t], 0, 0, 0);
          sc[1][t] = __builtin_amdgcn_mfma_f32_16x16x32_bf16(kf, qf[1][c], sc[1][t], 0, 0, 0);
        }
      if (kv0 + 31 > q0) {  // diagonal tiles only
#pragma unroll
        for (int u = 0; u < 2; ++u) {
          const int qrow = q0 + u * 16 + lo;
#pragma unroll
          for (int t = 0; t < 2; ++t)
#pragma unroll
            for (int j = 0; j < 4; ++j)
              if (kv0 + t * 16 + hi * 4 + j > qrow) sc[u][t][j] = -INFINITY;
        }
      }
#pragma unroll
      for (int u = 0; u < 2; ++u) {
        float tm = -INFINITY;
#pragma unroll
        for (int t = 0; t < 2; ++t)
#pragma unroll
          for (int j = 0; j < 4; ++j) tm = fmaxf(tm, sc[u][t][j]);
        tm = fmaxf(tm, __shfl_xor(tm, 16));
        tm = fmaxf(tm, __shfl_xor(tm, 32));
        // defer-rescale: only rescale when tile max exceeds running max + 8
        if (!__all(tm <= mrun[u] + 8.f)) {
          const float nm = fmaxf(mrun[u], tm);
          const float corr = exp2f(mrun[u] - nm);
          mrun[u] = nm;
          lrun[u] *= corr;
#pragma unroll
          for (int c = 0; c < 10; ++c) acc[c][u] *= corr;
        }
        float ps = 0.f;
        float p[2][4];
#pragma unroll
        for (int t = 0; t < 2; ++t)
#pragma unroll
          for (int j = 0; j < 4; ++j) { p[t][j] = exp2f(sc[u][t][j] - mrun[u]); ps += p[t][j]; }
        ps += __shfl_xor(ps, 16);
        ps += __shfl_xor(ps, 32);
        lrun[u] += ps;
#pragma unroll
        for (int t = 0; t < 2; ++t) {
          s4v w = { (short)f2b(p[t][0]), (short)f2b(p[t][1]),
                    (short)f2b(p[t][2]), (short)f2b(p[t][3]) };
          *(s4v*)&Pl[wid][u][lo][t * 16 + hi * 4] = w;
        }
      }
      // re-fragment P: lane holds q=lo, kv = hi*8 .. +7
      s8v pf[2];
#pragma unroll
      for (int u = 0; u < 2; ++u)
        pf[u] = *(const s8v*)&Pl[wid][u][lo][hi * 8];
      // Y^T += V^T . P^T ; vf: row d = c*16+lo, kv slot hi ^ (lo&3)
#pragma unroll
      for (int c = 0; c < 10; ++c) {
        s8v vf = *(const s8v*)&Vc[(((c * 16 + lo) * 4) + (hi ^ (lo & 3))) * 8];
        acc[c][0] = __builtin_amdgcn_mfma_f32_16x16x32_bf16(vf, pf[0], acc[c][0], 0, 0, 0);
        acc[c][1] = __builtin_amdgcn_mfma_f32_16x16x32_bf16(vf, pf[1], acc[c][1], 0, 0, 0);
      }
    }
    cur ^= 1;
  }
#undef STAGEKV

  // epilogue: Y[b][t][h*148 + d] bf16, divide by l, skip pad d >= 148
  const int b = bh >> 3, h = bh & 7;
#pragma unroll
  for (int u = 0; u < 2; ++u) {
    const float inv = 1.0f / lrun[u];
    const int trow = q0 + u * 16 + lo;
    const size_t ybase = ((size_t)(b * T_ + trow)) * C_ + h * DK_;
#pragma unroll
    for (int c = 0; c < 10; ++c) {
      const int d0 = c * 16 + hi * 4;
      if (d0 + 3 < DK_) {
        s4v o = { (short)f2b(acc[c][u][0] * inv), (short)f2b(acc[c][u][1] * inv),
                  (short)f2b(acc[c][u][2] * inv), (short)f2b(acc[c][u][3] * inv) };
        *(s4v*)(Y + ybase + d0) = o;
      }
    }
  }
}

extern "C" void kernel_launch(void* const* d_in, const int* in_sizes, int n_in,
                              void* d_out, int out_size, void* d_ws, size_t ws_size,
                              hipStream_t stream) {
  const float* x  = (const float*)d_in[0];
  const float* wA = (const float*)d_in[1];
  const float* bA = (const float*)d_in[2];
  const float* wP = (const float*)d_in[3];
  const float* bP = (const float*)d_in[4];
  float* out = (float*)d_out;

  short* ws  = (short*)d_ws;
  short* xb  = ws;                  // [8192][1184] bf16; later reused as Y
  short* wab = xb + 9699328;        // [3584][1184]
  short* wpb = wab + 4243456;       // [1280][1184]
  short* Qb  = wpb + 1515520;       // [32][2048][160]
  short* Kb  = Qb + 10485760;       // [32][2048][160]
  short* Vt  = Kb + 10485760;       // [32][160][2048]

  cvt4<<<(9699328 / 4 + 255) / 256, 256, 0, stream>>>(x, xb, 9699328 / 4);
  cvt4<<<(4205568 / 4 + 255) / 256, 256, 0, stream>>>(wA, wab, 4205568 / 4);
  cvt4<<<(1401856 / 4 + 255) / 256, 256, 0, stream>>>(wP, wpb, 1401856 / 4);
  zpad<<<256, 256, 0, stream>>>(Qb, Kb);  // zero d=148..159 contraction pads

  gemm_bt<0, 28><<<1792, 256, 0, stream>>>(xb, wab, bA, Qb, Kb, Vt, nullptr);
  attn<<<512, 256, 0, stream>>>(Qb, Kb, Vt, xb);  // Y aliases xb (dead)
  gemm_bt<1, 10><<<640, 256, 0, stream>>>(xb, wpb, bP, nullptr, nullptr, nullptr, out);
}

// Round 5
// 250.740 us; speedup vs baseline: 1.6936x; 1.6936x over previous
//
#include <hip/hip_runtime.h>
#include <stdint.h>

#define B_ 4
#define H_ 8
#define T_ 2048
#define C_ 1184
#define DK_ 148
#define DP_ 160
#define C3_ 3552

typedef __attribute__((ext_vector_type(8))) short s8v;
typedef __attribute__((ext_vector_type(4))) short s4v;
typedef __attribute__((ext_vector_type(4))) float f4v;
typedef __attribute__((ext_vector_type(16))) float f16v;

#define CSC 0.11858886f  /* log2(e)/sqrt(148) */

__device__ __forceinline__ unsigned short f2b(float f) {
  union { float f; unsigned u; } v; v.f = f;
  unsigned r = v.u + 0x7FFFu + ((v.u >> 16) & 1u);
  return (unsigned short)(r >> 16);
}

__device__ __forceinline__ void gld16(const void* g, void* l) {
  __builtin_amdgcn_global_load_lds(
      (const __attribute__((address_space(1))) void*)g,
      (__attribute__((address_space(3))) void*)l, 16, 0, 0);
}

__global__ __launch_bounds__(256) void cvt4(const float* __restrict__ src,
                                            short* __restrict__ dst, int n4) {
  int i = blockIdx.x * 256 + threadIdx.x;
  if (i >= n4) return;
  float4 f = ((const float4*)src)[i];
  s4v o = { (short)f2b(f.x), (short)f2b(f.y), (short)f2b(f.z), (short)f2b(f.w) };
  ((s4v*)dst)[i] = o;
}

// zero the d=148..159 pad of every Q/K row (contraction pads must be 0)
__global__ __launch_bounds__(256) void zpad(short* __restrict__ Qb,
                                            short* __restrict__ Kb) {
  const int row = blockIdx.x * 256 + threadIdx.x;  // 32*2048 rows
  const size_t off = (size_t)row * DP_ + DK_;
  const s4v z = { 0, 0, 0, 0 };
  *(s4v*)(Qb + off) = z; *(s4v*)(Qb + off + 4) = z; *(s4v*)(Qb + off + 8) = z;
  *(s4v*)(Kb + off) = z; *(s4v*)(Kb + off + 4) = z; *(s4v*)(Kb + off + 8) = z;
}

// C = A @ B^T (+bias). 128x128 tile, 4 waves, mfma 16x16x32 bf16, BK=32,
// global_load_lds(16B) staging, double-buffered. XCD-chunked 1D grid.
template <int EPI, int NT>
__global__ __launch_bounds__(256, 2) void gemm_bt(
    const short* __restrict__ A, const short* __restrict__ Bm,
    const float* __restrict__ bias,
    short* __restrict__ Qb, short* __restrict__ Kb, short* __restrict__ Vt,
    float* __restrict__ Out) {
  constexpr int K = C_;
  constexpr int NK = K / 32;  // 37
  __shared__ short As[2][128 * 32];
  __shared__ short Bs[2][128 * 32];
  const int tid = threadIdx.x;
  const int lane = tid & 63;
  const int wid = tid >> 6;
  const int lo = lane & 15, hi = lane >> 4;
  const int bid = blockIdx.x;
  const int xcd = bid & 7;
  const int kk = bid >> 3;
  const int m0 = (xcd * 8 + kk / NT) * 128;
  const int n0 = (kk % NT) * 128;
  const int wr = wid >> 1, wc = wid & 1;

  const int r0 = tid >> 2;
  const int sg = (tid & 3) * 8;
  const short* pa0 = A + (size_t)(m0 + r0) * K + sg;
  const short* pa1 = A + (size_t)(m0 + r0 + 64) * K + sg;
  const short* pb0 = Bm + (size_t)(n0 + r0) * K + sg;
  const short* pb1 = Bm + (size_t)(n0 + r0 + 64) * K + sg;

  f4v acc[4][4] = {};

#define STAGE(kk_, buf)                               \
  do {                                                \
    const int _o = (kk_) * 32;                        \
    gld16(pa0 + _o, &As[(buf)][tid * 8]);             \
    gld16(pa1 + _o, &As[(buf)][(tid + 256) * 8]);     \
    gld16(pb0 + _o, &Bs[(buf)][tid * 8]);             \
    gld16(pb1 + _o, &Bs[(buf)][(tid + 256) * 8]);     \
  } while (0)

  STAGE(0, 0);
  int cur = 0;
  for (int ks = 0; ks < NK; ++ks) {
    __syncthreads();  // drains vmcnt -> buf[cur] ready; buf[cur^1] consumed
    if (ks + 1 < NK) STAGE(ks + 1, cur ^ 1);
    const short* Ab = As[cur];
    const short* Bb = Bs[cur];
    s8v af[4], bf[4];
#pragma unroll
    for (int m = 0; m < 4; ++m)
      af[m] = *(const s8v*)&Ab[(wr * 64 + m * 16 + lo) * 32 + hi * 8];
#pragma unroll
    for (int n = 0; n < 4; ++n)
      bf[n] = *(const s8v*)&Bb[(wc * 64 + n * 16 + lo) * 32 + hi * 8];
#pragma unroll
    for (int m = 0; m < 4; ++m)
#pragma unroll
      for (int n = 0; n < 4; ++n)
        acc[m][n] = __builtin_amdgcn_mfma_f32_16x16x32_bf16(af[m], bf[n], acc[m][n], 0, 0, 0);
    cur ^= 1;
  }
#undef STAGE

#pragma unroll
  for (int n = 0; n < 4; ++n) {
    const int gn = n0 + wc * 64 + n * 16 + lo;
    if (EPI == 0) {
      if (gn < C3_) {
        const float bv = bias[gn];
        const int sel = gn / C_;
        const int r = gn - sel * C_;
        const int h = r / DK_;
        const int d = r - h * DK_;
#pragma unroll
        for (int m = 0; m < 4; ++m) {
          const int t0 = m0 + wr * 64 + m * 16 + hi * 4;
          const int b = t0 >> 11, tt = t0 & 2047;
          const int bh = b * H_ + h;
          if (sel == 2) {  // V^T: 4 consecutive t for fixed d -> vector store
            s4v o = { (short)f2b(acc[m][n][0] + bv), (short)f2b(acc[m][n][1] + bv),
                      (short)f2b(acc[m][n][2] + bv), (short)f2b(acc[m][n][3] + bv) };
            *(s4v*)&Vt[((size_t)bh * DP_ + d) * T_ + tt] = o;
          } else {
#pragma unroll
            for (int j = 0; j < 4; ++j) {
              const short v = (sel == 0) ? (short)f2b((acc[m][n][j] + bv) * CSC)
                                         : (short)f2b(acc[m][n][j] + bv);
              if (sel == 0) Qb[((size_t)bh * T_ + tt + j) * DP_ + d] = v;
              else          Kb[((size_t)bh * T_ + tt + j) * DP_ + d] = v;
            }
          }
        }
      }
    } else {
      if (gn < C_) {
        const float bv = bias[gn];
#pragma unroll
        for (int m = 0; m < 4; ++m)
#pragma unroll
          for (int j = 0; j < 4; ++j) {
            const int gm = m0 + wr * 64 + m * 16 + hi * 4 + j;
            Out[(size_t)gm * C_ + gn] = acc[m][n][j] + bv;
          }
      }
    }
  }
}

// Causal flash attention, 32x32x16 MFMA path, no P LDS round-trip.
// Q (pre-scaled), K: [32][2048][160] bf16 (d pad zeroed), Vt: [32][160][2048].
// Block = 4 waves x 32 q rows; kv tiles of 64, double-buffered global_load_lds
// (source-side XOR swizzle, round-3 layout); LDS = 80KB -> 2 blocks/CU.
// S^T via mfma32(K,Q): lane(q=l&31,h=l>>5) holds kv=(r&3)+8(r>>2)+4h per tile.
// PV B-frag built in-register: 4 cvt-packs + 4 shfl_xor(32) + 4 selects/step.
__global__ __launch_bounds__(256, 2) void attn(
    const short* __restrict__ Qb, const short* __restrict__ Kb,
    const short* __restrict__ Vt, short* __restrict__ Y) {
  __shared__ short Ks[2][10240];  // [5 c][64 r][4 w] granules(8sh), w ^= (r>>1)&3
  __shared__ short Vs[2][10240];  // [160 d][8 v] granules, v ^= d&7
  const int tid = threadIdx.x;
  const int lane = tid & 63;
  const int wid = tid >> 6;
  const int q31 = lane & 31;
  const int h32 = lane >> 5;
  // XCD-aware balanced remap: xcd owns 4 bh; qb paired with 15-qb
  const int s = blockIdx.x;
  const int xcd = s & 7;
  const int k = s >> 3;
  int qb, bsub;
  if (k < 32) { bsub = k >> 4; qb = k & 15; }
  else { bsub = 2 + ((k - 32) >> 4); qb = 15 - (k & 15); }
  const int bh = xcd * 4 + bsub;
  const int q0 = qb * 128 + wid * 32;
  const short* Qh = Qb + (size_t)bh * T_ * DP_;
  const short* Kh = Kb + (size_t)bh * T_ * DP_;
  const short* Vh = Vt + (size_t)bh * DP_ * T_;

  // Q B-fragments (32x32x16): lane holds q=q0+q31, k-step c16: d = c16*16+h32*8+e
  s8v qf[10];
#pragma unroll
  for (int c = 0; c < 10; ++c)
    qf[c] = *(const s8v*)(Qh + (size_t)(q0 + q31) * DP_ + c * 16 + h32 * 8);

  f16v acc[5] = {};  // Y^T: acc[dt] reg r: d = dt*32+(r&3)+8(r>>2)+4h32, q = q31
  float mrun = -INFINITY, lrun = 0.f;
  const int nt = 2 * (qb + 1);  // kv tiles of 64, uniform across block

#define STAGEKV(kt_, buf_)                                                   \
  do {                                                                       \
    const size_t kvo_ = (size_t)(kt_) * 64;                                  \
    _Pragma("unroll")                                                        \
    for (int i_ = 0; i_ < 5; ++i_) {                                         \
      const int g_ = tid + i_ * 256;                                         \
      const int c_ = g_ >> 8, re_ = g_ & 255, r_ = re_ >> 2, wz_ = re_ & 3;  \
      const int w_ = wz_ ^ ((r_ >> 1) & 3);                                  \
      gld16(Kh + (kvo_ + r_) * DP_ + c_ * 32 + w_ * 8, &Ks[buf_][g_ * 8]);   \
      const int d_ = g_ >> 3, vz_ = g_ & 7;                                  \
      const int v_ = vz_ ^ (d_ & 7);                                         \
      gld16(Vh + (size_t)d_ * T_ + kvo_ + v_ * 8, &Vs[buf_][g_ * 8]);        \
    }                                                                        \
  } while (0)

  STAGEKV(0, 0);
  int cur = 0;
  for (int kt = 0; kt < nt; ++kt) {
    __syncthreads();  // stage of buf[cur] drained; buf[cur^1] free
    if (kt + 1 < nt) STAGEKV(kt + 1, cur ^ 1);
    const int kv0 = kt * 64;
    if (kv0 <= q0 + 31) {  // wave-uniform: skip fully-masked tail tiles
      const short* Kc = Ks[cur];
      const short* Vc = Vs[cur];
      // S^T[kv][q]: 2 tiles of 32 kv; A=K rows kv, B=Q cols q, k=d (10 steps)
      f16v sc[2] = {};
      __builtin_amdgcn_s_setprio(1);
#pragma unroll
      for (int t2 = 0; t2 < 2; ++t2) {
        const int r_ = t2 * 32 + q31;
#pragma unroll
        for (int c16 = 0; c16 < 10; ++c16) {
          const int u_ = 2 * c16 + h32;
          const int w_ = (u_ & 3) ^ ((r_ >> 1) & 3);
          s8v kf = *(const s8v*)&Kc[((u_ >> 2) * 256 + r_ * 4 + w_) * 8];
          sc[t2] = __builtin_amdgcn_mfma_f32_32x32x16_bf16(kf, qf[c16], sc[t2], 0, 0, 0);
        }
      }
      __builtin_amdgcn_s_setprio(0);
      // causal mask (diagonal tiles only): kv = kv0+t2*32+(r&3)+8(r>>2)+4h32
      const int qrow = q0 + q31;
      if (kv0 + 63 > q0) {
#pragma unroll
        for (int t2 = 0; t2 < 2; ++t2)
#pragma unroll
          for (int g = 0; g < 4; ++g)
#pragma unroll
            for (int j = 0; j < 4; ++j)
              if (kv0 + t2 * 32 + 8 * g + 4 * h32 + j > qrow)
                sc[t2][4 * g + j] = -INFINITY;
      }
      // online softmax over 32 values; one cross-half shuffle per reduce
      float tm = -INFINITY;
#pragma unroll
      for (int t2 = 0; t2 < 2; ++t2)
#pragma unroll
        for (int r = 0; r < 16; ++r) tm = fmaxf(tm, sc[t2][r]);
      tm = fmaxf(tm, __shfl_xor(tm, 32));
      if (!__all(tm <= mrun + 8.f)) {  // defer-rescale THR=8
        const float nm = fmaxf(mrun, tm);
        const float corr = exp2f(mrun - nm);
        mrun = nm;
        lrun *= corr;
#pragma unroll
        for (int dt = 0; dt < 5; ++dt)
#pragma unroll
          for (int r = 0; r < 16; ++r) acc[dt][r] *= corr;
      }
      float ps = 0.f;
#pragma unroll
      for (int t2 = 0; t2 < 2; ++t2)
#pragma unroll
        for (int r = 0; r < 16; ++r) {
          sc[t2][r] = exp2f(sc[t2][r] - mrun);
          ps += sc[t2][r];
        }
      ps += __shfl_xor(ps, 32);
      lrun += ps;
      // PV: 4 k-steps of 16 kv; B-frag via pack + butterfly exchange
#pragma unroll
      for (int st = 0; st < 4; ++st) {
        const int t2 = st >> 1, g4 = (st & 1) * 8;
        unsigned wA0 = (unsigned)f2b(sc[t2][g4 + 0]) | ((unsigned)f2b(sc[t2][g4 + 1]) << 16);
        unsigned wA1 = (unsigned)f2b(sc[t2][g4 + 2]) | ((unsigned)f2b(sc[t2][g4 + 3]) << 16);
        unsigned wB0 = (unsigned)f2b(sc[t2][g4 + 4]) | ((unsigned)f2b(sc[t2][g4 + 5]) << 16);
        unsigned wB1 = (unsigned)f2b(sc[t2][g4 + 6]) | ((unsigned)f2b(sc[t2][g4 + 7]) << 16);
        const unsigned sxA0 = (unsigned)__shfl_xor((int)wA0, 32);
        const unsigned sxA1 = (unsigned)__shfl_xor((int)wA1, 32);
        const unsigned sxB0 = (unsigned)__shfl_xor((int)wB0, 32);
        const unsigned sxB1 = (unsigned)__shfl_xor((int)wB1, 32);
        union { unsigned w[4]; s8v v; } pf;
        pf.w[0] = h32 ? sxB0 : wA0;
        pf.w[1] = h32 ? sxB1 : wA1;
        pf.w[2] = h32 ? wB0 : sxA0;
        pf.w[3] = h32 ? wB1 : sxA1;
        // A=V^T: row d = dt*32+q31, k: kv = st*16+h32*8+e
        __builtin_amdgcn_s_setprio(1);
#pragma unroll
        for (int dt = 0; dt < 5; ++dt) {
          const int d_ = dt * 32 + q31;
          const int sl_ = (st * 2 + h32) ^ (d_ & 7);
          s8v vf = *(const s8v*)&Vc[(d_ * 8 + sl_) * 8];
          acc[dt] = __builtin_amdgcn_mfma_f32_32x32x16_bf16(vf, pf.v, acc[dt], 0, 0, 0);
        }
        __builtin_amdgcn_s_setprio(0);
      }
    }
    cur ^= 1;
  }
#undef STAGEKV

  // epilogue: Y[b][t][h*148 + d] bf16, divide by l, skip pad d >= 148
  const float inv = 1.0f / lrun;
  const int b = bh >> 3, h = bh & 7;
  const int trow = q0 + q31;
  const size_t ybase = ((size_t)(b * T_ + trow)) * C_ + h * DK_;
#pragma unroll
  for (int dt = 0; dt < 5; ++dt)
#pragma unroll
    for (int g = 0; g < 4; ++g) {
      const int d0 = dt * 32 + 8 * g + 4 * h32;
      if (d0 + 3 < DK_) {
        s4v o = { (short)f2b(acc[dt][4 * g + 0] * inv), (short)f2b(acc[dt][4 * g + 1] * inv),
                  (short)f2b(acc[dt][4 * g + 2] * inv), (short)f2b(acc[dt][4 * g + 3] * inv) };
        *(s4v*)(Y + ybase + d0) = o;
      }
    }
}

extern "C" void kernel_launch(void* const* d_in, const int* in_sizes, int n_in,
                              void* d_out, int out_size, void* d_ws, size_t ws_size,
                              hipStream_t stream) {
  const float* x  = (const float*)d_in[0];
  const float* wA = (const float*)d_in[1];
  const float* bA = (const float*)d_in[2];
  const float* wP = (const float*)d_in[3];
  const float* bP = (const float*)d_in[4];
  float* out = (float*)d_out;

  short* ws  = (short*)d_ws;
  short* xb  = ws;                  // [8192][1184] bf16; later reused as Y
  short* wab = xb + 9699328;        // [3584][1184]
  short* wpb = wab + 4243456;       // [1280][1184]
  short* Qb  = wpb + 1515520;       // [32][2048][160]
  short* Kb  = Qb + 10485760;       // [32][2048][160]
  short* Vt  = Kb + 10485760;       // [32][160][2048]

  cvt4<<<(9699328 / 4 + 255) / 256, 256, 0, stream>>>(x, xb, 9699328 / 4);
  cvt4<<<(4205568 / 4 + 255) / 256, 256, 0, stream>>>(wA, wab, 4205568 / 4);
  cvt4<<<(1401856 / 4 + 255) / 256, 256, 0, stream>>>(wP, wpb, 1401856 / 4);
  zpad<<<256, 256, 0, stream>>>(Qb, Kb);  // zero d=148..159 contraction pads

  gemm_bt<0, 28><<<1792, 256, 0, stream>>>(xb, wab, bA, Qb, Kb, Vt, nullptr);
  attn<<<512, 256, 0, stream>>>(Qb, Kb, Vt, xb);  // Y aliases xb (dead)
  gemm_bt<1, 10><<<640, 256, 0, stream>>>(xb, wpb, bP, nullptr, nullptr, nullptr, out);
}

// Round 6
// 247.561 us; speedup vs baseline: 1.7153x; 1.0128x over previous
//
#include <hip/hip_runtime.h>
#include <stdint.h>

#define B_ 4
#define H_ 8
#define T_ 2048
#define C_ 1184
#define DK_ 148
#define DP_ 160
#define C3_ 3552

typedef __attribute__((ext_vector_type(8))) short s8v;
typedef __attribute__((ext_vector_type(4))) short s4v;
typedef __attribute__((ext_vector_type(4))) float f4v;
typedef __attribute__((ext_vector_type(16))) float f16v;

#define CSC 0.11858886f  /* log2(e)/sqrt(148) */

__device__ __forceinline__ unsigned short f2b(float f) {
  union { float f; unsigned u; } v; v.f = f;
  unsigned r = v.u + 0x7FFFu + ((v.u >> 16) & 1u);
  return (unsigned short)(r >> 16);
}

__device__ __forceinline__ void gld16(const void* g, void* l) {
  __builtin_amdgcn_global_load_lds(
      (const __attribute__((address_space(1))) void*)g,
      (__attribute__((address_space(3))) void*)l, 16, 0, 0);
}

__global__ __launch_bounds__(256) void cvt4(const float* __restrict__ src,
                                            short* __restrict__ dst, int n4) {
  int i = blockIdx.x * 256 + threadIdx.x;
  if (i >= n4) return;
  float4 f = ((const float4*)src)[i];
  s4v o = { (short)f2b(f.x), (short)f2b(f.y), (short)f2b(f.z), (short)f2b(f.w) };
  ((s4v*)dst)[i] = o;
}

// zero the d=148..159 pad of every Q/K row (contraction pads must be 0)
__global__ __launch_bounds__(256) void zpad(short* __restrict__ Qb,
                                            short* __restrict__ Kb) {
  const int row = blockIdx.x * 256 + threadIdx.x;  // 32*2048 rows
  const size_t off = (size_t)row * DP_ + DK_;
  const s4v z = { 0, 0, 0, 0 };
  *(s4v*)(Qb + off) = z; *(s4v*)(Qb + off + 4) = z; *(s4v*)(Qb + off + 8) = z;
  *(s4v*)(Kb + off) = z; *(s4v*)(Kb + off + 4) = z; *(s4v*)(Kb + off + 8) = z;
}

// ---------------------------------------------------------------------------
// QKV GEMM: C = A @ B^T + bias, scatter epilogue to Q/K/V^T.
// 256x256 tile, 8 waves (2Mx4N), BK=32, mfma 16x16x32 bf16.
// T3+T4: 3 LDS K-tile buffers, stage 2 tiles ahead, counted vmcnt(4) per tile
// (drain-to-next-tile-ready before the tile-boundary barrier), raw s_barrier,
// 2 phases/tile of 16 MFMA each. T2: granule-XOR swizzle (read + source side).
// T5: setprio around MFMA clusters. LDS 96KB -> 1 block/CU (8 waves).
// ---------------------------------------------------------------------------
#define SWZ(r) ((((r) & 3) ^ (((r) >> 2) & 3)))
template <int NT>
__global__ __launch_bounds__(512, 2) void gemm_qkv8(
    const short* __restrict__ A, const short* __restrict__ Bm,
    const float* __restrict__ bias,
    short* __restrict__ Qb, short* __restrict__ Kb, short* __restrict__ Vt) {
  constexpr int NKT = C_ / 32;  // 37
  __shared__ short As[3][256 * 32];
  __shared__ short Bs[3][256 * 32];
  const int tid = threadIdx.x;       // 0..511
  const int lane = tid & 63;
  const int wid = tid >> 6;          // 0..7
  const int lo = lane & 15, hi = lane >> 4;
  const int wr = wid >> 2, wc = wid & 3;  // 2 x 4 wave grid
  const int bid = blockIdx.x;
  const int xcd = bid & 7, kk = bid >> 3;
  const int m0 = (xcd * 4 + kk / NT) * 256;
  const int n0 = (kk % NT) * 256;

  // staging: granule g in [0,1024): row g>>2, LDS slot g&3,
  // source segment = slot ^ SWZ(row)  (self-inverse on read side)
  const int rS = tid >> 2, uS = tid & 3;
  const int seg = (uS ^ SWZ(rS)) * 8;
  const short* paw0 = A + (size_t)(m0 + rS) * C_ + seg;
  const short* paw1 = A + (size_t)(m0 + rS + 128) * C_ + seg;  // SWZ(r+128)==SWZ(r)
  const short* pbw0 = Bm + (size_t)(n0 + rS) * C_ + seg;
  const short* pbw1 = Bm + (size_t)(n0 + rS + 128) * C_ + seg;

#define STGA(kk_, buf_)                                   \
  do {                                                    \
    gld16(paw0 + (kk_) * 32, &As[buf_][tid * 8]);         \
    gld16(paw1 + (kk_) * 32, &As[buf_][(tid + 512) * 8]); \
  } while (0)
#define STGB(kk_, buf_)                                   \
  do {                                                    \
    gld16(pbw0 + (kk_) * 32, &Bs[buf_][tid * 8]);         \
    gld16(pbw1 + (kk_) * 32, &Bs[buf_][(tid + 512) * 8]); \
  } while (0)

  f4v acc[8][4] = {};
  const int swzl = SWZ(lo);  // row bits 0..3 come from lo only

  // prologue: tiles 0,1 in flight; wait tile0 (keep tile1's 4 outstanding)
  STGA(0, 0); STGB(0, 0);
  STGA(1, 1); STGB(1, 1);
  asm volatile("s_waitcnt vmcnt(4)" ::: "memory");
  __builtin_amdgcn_s_barrier();

  int cur = 0;
  for (int t = 0; t < NKT; ++t) {
    const short* Ab = As[cur];
    const short* Bb = Bs[cur];
    int nxt = cur + 2; if (nxt >= 3) nxt -= 3;
    const bool pf = (t + 2 < NKT);

    // ---- phase 0: a-frags m0..3 + b-frags, stage A(t+2), 16 MFMA ----
    s8v af[4], bf[4];
#pragma unroll
    for (int m = 0; m < 4; ++m) {
      const int r = wr * 128 + m * 16 + lo;
      af[m] = *(const s8v*)&Ab[(r * 4 + (hi ^ swzl)) * 8];
    }
#pragma unroll
    for (int n = 0; n < 4; ++n) {
      const int r = wc * 64 + n * 16 + lo;
      bf[n] = *(const s8v*)&Bb[(r * 4 + (hi ^ swzl)) * 8];
    }
    if (pf) STGA(t + 2, nxt);
    __builtin_amdgcn_s_barrier();
    __builtin_amdgcn_s_setprio(1);
#pragma unroll
    for (int m = 0; m < 4; ++m)
#pragma unroll
      for (int n = 0; n < 4; ++n)
        acc[m][n] = __builtin_amdgcn_mfma_f32_16x16x32_bf16(af[m], bf[n], acc[m][n], 0, 0, 0);
    __builtin_amdgcn_s_setprio(0);
    __builtin_amdgcn_s_barrier();

    // ---- phase 1: a-frags m4..7 (b reused in regs), stage B(t+2), 16 MFMA ----
    s8v ag[4];
#pragma unroll
    for (int m = 0; m < 4; ++m) {
      const int r = wr * 128 + 64 + m * 16 + lo;
      ag[m] = *(const s8v*)&Ab[(r * 4 + (hi ^ swzl)) * 8];
    }
    if (pf) STGB(t + 2, nxt);
    __builtin_amdgcn_s_barrier();
    __builtin_amdgcn_s_setprio(1);
#pragma unroll
    for (int m = 0; m < 4; ++m)
#pragma unroll
      for (int n = 0; n < 4; ++n)
        acc[m + 4][n] = __builtin_amdgcn_mfma_f32_16x16x32_bf16(ag[m], bf[n], acc[m + 4][n], 0, 0, 0);
    __builtin_amdgcn_s_setprio(0);
    // tile boundary: ensure tile t+1 fully landed (keep t+2's 4 loads in
    // flight), then barrier publishes it across waves
    if (pf) asm volatile("s_waitcnt vmcnt(4)" ::: "memory");
    else    asm volatile("s_waitcnt vmcnt(0)" ::: "memory");
    __builtin_amdgcn_s_barrier();
    cur = (cur + 1 == 3) ? 0 : cur + 1;
  }
#undef STGA
#undef STGB

  // epilogue: scatter to Q (scaled), K, V^T
#pragma unroll
  for (int n = 0; n < 4; ++n) {
    const int gn = n0 + wc * 64 + n * 16 + lo;
    if (gn < C3_) {
      const float bv = bias[gn];
      const int sel = gn / C_;
      const int r = gn - sel * C_;
      const int h = r / DK_;
      const int d = r - h * DK_;
#pragma unroll
      for (int m = 0; m < 8; ++m) {
        const int t0 = m0 + wr * 128 + ((m & 3) * 16) + ((m >> 2) * 64) + hi * 4;
        const int b = t0 >> 11, tt = t0 & 2047;
        const int bh = b * H_ + h;
        const int mi = (m < 4) ? m : m;  // acc row index == m (0..7)
        if (sel == 2) {  // V^T: 4 consecutive t for fixed d -> vector store
          s4v o = { (short)f2b(acc[mi][n][0] + bv), (short)f2b(acc[mi][n][1] + bv),
                    (short)f2b(acc[mi][n][2] + bv), (short)f2b(acc[mi][n][3] + bv) };
          *(s4v*)&Vt[((size_t)bh * DP_ + d) * T_ + tt] = o;
        } else {
#pragma unroll
          for (int j = 0; j < 4; ++j) {
            const short v = (sel == 0) ? (short)f2b((acc[mi][n][j] + bv) * CSC)
                                       : (short)f2b(acc[mi][n][j] + bv);
            if (sel == 0) Qb[((size_t)bh * T_ + tt + j) * DP_ + d] = v;
            else          Kb[((size_t)bh * T_ + tt + j) * DP_ + d] = v;
          }
        }
      }
    }
  }
}
// NOTE on acc row mapping above: phase0 filled acc[0..3] = m-frags 0..3 (rows
// wr*128 + m*16), phase1 filled acc[4..7] = m-frags at rows wr*128+64+m*16.
// t0 formula: (m&3)*16 + (m>>2)*64 reproduces exactly that mapping.

// C = A @ B^T (+bias). 128x128 tile, 4 waves, mfma 16x16x32 bf16, BK=32,
// global_load_lds(16B) staging, double-buffered. XCD-chunked 1D grid.
// (kept for the out-projection)
template <int NT>
__global__ __launch_bounds__(256, 2) void gemm_bt(
    const short* __restrict__ A, const short* __restrict__ Bm,
    const float* __restrict__ bias, float* __restrict__ Out) {
  constexpr int K = C_;
  constexpr int NK = K / 32;  // 37
  __shared__ short As[2][128 * 32];
  __shared__ short Bs[2][128 * 32];
  const int tid = threadIdx.x;
  const int lane = tid & 63;
  const int wid = tid >> 6;
  const int lo = lane & 15, hi = lane >> 4;
  const int bid = blockIdx.x;
  const int xcd = bid & 7;
  const int kk = bid >> 3;
  const int m0 = (xcd * 8 + kk / NT) * 128;
  const int n0 = (kk % NT) * 128;
  const int wr = wid >> 1, wc = wid & 1;

  const int r0 = tid >> 2;
  const int sg = (tid & 3) * 8;
  const short* pa0 = A + (size_t)(m0 + r0) * K + sg;
  const short* pa1 = A + (size_t)(m0 + r0 + 64) * K + sg;
  const short* pb0 = Bm + (size_t)(n0 + r0) * K + sg;
  const short* pb1 = Bm + (size_t)(n0 + r0 + 64) * K + sg;

  f4v acc[4][4] = {};

#define STAGE(kk_, buf)                               \
  do {                                                \
    const int _o = (kk_) * 32;                        \
    gld16(pa0 + _o, &As[(buf)][tid * 8]);             \
    gld16(pa1 + _o, &As[(buf)][(tid + 256) * 8]);     \
    gld16(pb0 + _o, &Bs[(buf)][tid * 8]);             \
    gld16(pb1 + _o, &Bs[(buf)][(tid + 256) * 8]);     \
  } while (0)

  STAGE(0, 0);
  int cur = 0;
  for (int ks = 0; ks < NK; ++ks) {
    __syncthreads();  // drains vmcnt -> buf[cur] ready; buf[cur^1] consumed
    if (ks + 1 < NK) STAGE(ks + 1, cur ^ 1);
    const short* Ab = As[cur];
    const short* Bb = Bs[cur];
    s8v af[4], bf[4];
#pragma unroll
    for (int m = 0; m < 4; ++m)
      af[m] = *(const s8v*)&Ab[(wr * 64 + m * 16 + lo) * 32 + hi * 8];
#pragma unroll
    for (int n = 0; n < 4; ++n)
      bf[n] = *(const s8v*)&Bb[(wc * 64 + n * 16 + lo) * 32 + hi * 8];
#pragma unroll
    for (int m = 0; m < 4; ++m)
#pragma unroll
      for (int n = 0; n < 4; ++n)
        acc[m][n] = __builtin_amdgcn_mfma_f32_16x16x32_bf16(af[m], bf[n], acc[m][n], 0, 0, 0);
    cur ^= 1;
  }
#undef STAGE

#pragma unroll
  for (int n = 0; n < 4; ++n) {
    const int gn = n0 + wc * 64 + n * 16 + lo;
    if (gn < C_) {
      const float bv = bias[gn];
#pragma unroll
      for (int m = 0; m < 4; ++m)
#pragma unroll
        for (int j = 0; j < 4; ++j) {
          const int gm = m0 + wr * 64 + m * 16 + hi * 4 + j;
          Out[(size_t)gm * C_ + gn] = acc[m][n][j] + bv;
        }
    }
  }
}

// Causal flash attention, 32x32x16 MFMA path, no P LDS round-trip.
// (unchanged from round 5)
__global__ __launch_bounds__(256, 2) void attn(
    const short* __restrict__ Qb, const short* __restrict__ Kb,
    const short* __restrict__ Vt, short* __restrict__ Y) {
  __shared__ short Ks[2][10240];  // [5 c][64 r][4 w] granules(8sh), w ^= (r>>1)&3
  __shared__ short Vs[2][10240];  // [160 d][8 v] granules, v ^= d&7
  const int tid = threadIdx.x;
  const int lane = tid & 63;
  const int wid = tid >> 6;
  const int q31 = lane & 31;
  const int h32 = lane >> 5;
  const int s = blockIdx.x;
  const int xcd = s & 7;
  const int k = s >> 3;
  int qb, bsub;
  if (k < 32) { bsub = k >> 4; qb = k & 15; }
  else { bsub = 2 + ((k - 32) >> 4); qb = 15 - (k & 15); }
  const int bh = xcd * 4 + bsub;
  const int q0 = qb * 128 + wid * 32;
  const short* Qh = Qb + (size_t)bh * T_ * DP_;
  const short* Kh = Kb + (size_t)bh * T_ * DP_;
  const short* Vh = Vt + (size_t)bh * DP_ * T_;

  s8v qf[10];
#pragma unroll
  for (int c = 0; c < 10; ++c)
    qf[c] = *(const s8v*)(Qh + (size_t)(q0 + q31) * DP_ + c * 16 + h32 * 8);

  f16v acc[5] = {};
  float mrun = -INFINITY, lrun = 0.f;
  const int nt = 2 * (qb + 1);

#define STAGEKV(kt_, buf_)                                                   \
  do {                                                                       \
    const size_t kvo_ = (size_t)(kt_) * 64;                                  \
    _Pragma("unroll")                                                        \
    for (int i_ = 0; i_ < 5; ++i_) {                                         \
      const int g_ = tid + i_ * 256;                                         \
      const int c_ = g_ >> 8, re_ = g_ & 255, r_ = re_ >> 2, wz_ = re_ & 3;  \
      const int w_ = wz_ ^ ((r_ >> 1) & 3);                                  \
      gld16(Kh + (kvo_ + r_) * DP_ + c_ * 32 + w_ * 8, &Ks[buf_][g_ * 8]);   \
      const int d_ = g_ >> 3, vz_ = g_ & 7;                                  \
      const int v_ = vz_ ^ (d_ & 7);                                         \
      gld16(Vh + (size_t)d_ * T_ + kvo_ + v_ * 8, &Vs[buf_][g_ * 8]);        \
    }                                                                        \
  } while (0)

  STAGEKV(0, 0);
  int cur = 0;
  for (int kt = 0; kt < nt; ++kt) {
    __syncthreads();
    if (kt + 1 < nt) STAGEKV(kt + 1, cur ^ 1);
    const int kv0 = kt * 64;
    if (kv0 <= q0 + 31) {
      const short* Kc = Ks[cur];
      const short* Vc = Vs[cur];
      f16v sc[2] = {};
      __builtin_amdgcn_s_setprio(1);
#pragma unroll
      for (int t2 = 0; t2 < 2; ++t2) {
        const int r_ = t2 * 32 + q31;
#pragma unroll
        for (int c16 = 0; c16 < 10; ++c16) {
          const int u_ = 2 * c16 + h32;
          const int w_ = (u_ & 3) ^ ((r_ >> 1) & 3);
          s8v kf = *(const s8v*)&Kc[((u_ >> 2) * 256 + r_ * 4 + w_) * 8];
          sc[t2] = __builtin_amdgcn_mfma_f32_32x32x16_bf16(kf, qf[c16], sc[t2], 0, 0, 0);
        }
      }
      __builtin_amdgcn_s_setprio(0);
      const int qrow = q0 + q31;
      if (kv0 + 63 > q0) {
#pragma unroll
        for (int t2 = 0; t2 < 2; ++t2)
#pragma unroll
          for (int g = 0; g < 4; ++g)
#pragma unroll
            for (int j = 0; j < 4; ++j)
              if (kv0 + t2 * 32 + 8 * g + 4 * h32 + j > qrow)
                sc[t2][4 * g + j] = -INFINITY;
      }
      float tm = -INFINITY;
#pragma unroll
      for (int t2 = 0; t2 < 2; ++t2)
#pragma unroll
        for (int r = 0; r < 16; ++r) tm = fmaxf(tm, sc[t2][r]);
      tm = fmaxf(tm, __shfl_xor(tm, 32));
      if (!__all(tm <= mrun + 8.f)) {
        const float nm = fmaxf(mrun, tm);
        const float corr = exp2f(mrun - nm);
        mrun = nm;
        lrun *= corr;
#pragma unroll
        for (int dt = 0; dt < 5; ++dt)
#pragma unroll
          for (int r = 0; r < 16; ++r) acc[dt][r] *= corr;
      }
      float ps = 0.f;
#pragma unroll
      for (int t2 = 0; t2 < 2; ++t2)
#pragma unroll
        for (int r = 0; r < 16; ++r) {
          sc[t2][r] = exp2f(sc[t2][r] - mrun);
          ps += sc[t2][r];
        }
      ps += __shfl_xor(ps, 32);
      lrun += ps;
#pragma unroll
      for (int st = 0; st < 4; ++st) {
        const int t2 = st >> 1, g4 = (st & 1) * 8;
        unsigned wA0 = (unsigned)f2b(sc[t2][g4 + 0]) | ((unsigned)f2b(sc[t2][g4 + 1]) << 16);
        unsigned wA1 = (unsigned)f2b(sc[t2][g4 + 2]) | ((unsigned)f2b(sc[t2][g4 + 3]) << 16);
        unsigned wB0 = (unsigned)f2b(sc[t2][g4 + 4]) | ((unsigned)f2b(sc[t2][g4 + 5]) << 16);
        unsigned wB1 = (unsigned)f2b(sc[t2][g4 + 6]) | ((unsigned)f2b(sc[t2][g4 + 7]) << 16);
        const unsigned sxA0 = (unsigned)__shfl_xor((int)wA0, 32);
        const unsigned sxA1 = (unsigned)__shfl_xor((int)wA1, 32);
        const unsigned sxB0 = (unsigned)__shfl_xor((int)wB0, 32);
        const unsigned sxB1 = (unsigned)__shfl_xor((int)wB1, 32);
        union { unsigned w[4]; s8v v; } pf;
        pf.w[0] = h32 ? sxB0 : wA0;
        pf.w[1] = h32 ? sxB1 : wA1;
        pf.w[2] = h32 ? wB0 : sxA0;
        pf.w[3] = h32 ? wB1 : sxA1;
        __builtin_amdgcn_s_setprio(1);
#pragma unroll
        for (int dt = 0; dt < 5; ++dt) {
          const int d_ = dt * 32 + q31;
          const int sl_ = (st * 2 + h32) ^ (d_ & 7);
          s8v vf = *(const s8v*)&Vc[(d_ * 8 + sl_) * 8];
          acc[dt] = __builtin_amdgcn_mfma_f32_32x32x16_bf16(vf, pf.v, acc[dt], 0, 0, 0);
        }
        __builtin_amdgcn_s_setprio(0);
      }
    }
    cur ^= 1;
  }
#undef STAGEKV

  const float inv = 1.0f / lrun;
  const int b = bh >> 3, h = bh & 7;
  const int trow = q0 + q31;
  const size_t ybase = ((size_t)(b * T_ + trow)) * C_ + h * DK_;
#pragma unroll
  for (int dt = 0; dt < 5; ++dt)
#pragma unroll
    for (int g = 0; g < 4; ++g) {
      const int d0 = dt * 32 + 8 * g + 4 * h32;
      if (d0 + 3 < DK_) {
        s4v o = { (short)f2b(acc[dt][4 * g + 0] * inv), (short)f2b(acc[dt][4 * g + 1] * inv),
                  (short)f2b(acc[dt][4 * g + 2] * inv), (short)f2b(acc[dt][4 * g + 3] * inv) };
        *(s4v*)(Y + ybase + d0) = o;
      }
    }
}

extern "C" void kernel_launch(void* const* d_in, const int* in_sizes, int n_in,
                              void* d_out, int out_size, void* d_ws, size_t ws_size,
                              hipStream_t stream) {
  const float* x  = (const float*)d_in[0];
  const float* wA = (const float*)d_in[1];
  const float* bA = (const float*)d_in[2];
  const float* wP = (const float*)d_in[3];
  const float* bP = (const float*)d_in[4];
  float* out = (float*)d_out;

  short* ws  = (short*)d_ws;
  short* xb  = ws;                  // [8192][1184] bf16; later reused as Y
  short* wab = xb + 9699328;        // [3584][1184]
  short* wpb = wab + 4243456;       // [1280][1184]
  short* Qb  = wpb + 1515520;       // [32][2048][160]
  short* Kb  = Qb + 10485760;       // [32][2048][160]
  short* Vt  = Kb + 10485760;       // [32][160][2048]

  cvt4<<<(9699328 / 4 + 255) / 256, 256, 0, stream>>>(x, xb, 9699328 / 4);
  cvt4<<<(4205568 / 4 + 255) / 256, 256, 0, stream>>>(wA, wab, 4205568 / 4);
  cvt4<<<(1401856 / 4 + 255) / 256, 256, 0, stream>>>(wP, wpb, 1401856 / 4);
  zpad<<<256, 256, 0, stream>>>(Qb, Kb);  // zero d=148..159 contraction pads

  // qkv: 32 m-tiles x 14 n-tiles, XCD-chunked (448 % 8 == 0)
  gemm_qkv8<14><<<448, 512, 0, stream>>>(xb, wab, bA, Qb, Kb, Vt);
  attn<<<512, 256, 0, stream>>>(Qb, Kb, Vt, xb);  // Y aliases xb (dead)
  gemm_bt<10><<<640, 256, 0, stream>>>(xb, wpb, bP, out);
}